// Round 1
// baseline (376.915 us; speedup 1.0000x reference)
//
#include <hip/hip_runtime.h>
#include <hip/hip_bf16.h>

#define BATCH  16384
#define NSITES 4096
#define HALFN  2048
#define HDIM   128
#define SLOPE  0.2f

typedef __attribute__((ext_vector_type(8))) short bf16x8;
typedef __attribute__((ext_vector_type(4))) float f32x4;

// ws layout (bf16 element offsets), all matrices stored TRANSPOSED as [N][K]
#define OFF_SW0T 0         // [128][2048]
#define OFF_TW0T 262144
#define OFF_SW1T 524288    // [128][128]
#define OFF_TW1T 540672
#define OFF_SW2T 557056    // [2048][128]
#define OFF_TW2T 819200
#define WS_ELEMS 1081344

__device__ __forceinline__ unsigned short f2bf(float f) {
    unsigned int u = __float_as_uint(f);
    u += 0x7FFFu + ((u >> 16) & 1u);   // round-to-nearest-even
    return (unsigned short)(u >> 16);
}

__global__ void conv_w(const float* __restrict__ sW0, const float* __restrict__ sW1,
                       const float* __restrict__ sW2, const float* __restrict__ tW0,
                       const float* __restrict__ tW1, const float* __restrict__ tW2,
                       unsigned short* __restrict__ ws) {
    const int total = 262144 + 16384 + 262144;
    for (int i = blockIdx.x * blockDim.x + threadIdx.x; i < total;
         i += gridDim.x * blockDim.x) {
        if (i < 262144) {                    // W0 [2048][128] -> [128][2048]
            int k = i >> 7, n = i & 127;
            ws[OFF_SW0T + n * 2048 + k] = f2bf(sW0[i]);
            ws[OFF_TW0T + n * 2048 + k] = f2bf(tW0[i]);
        } else if (i < 262144 + 16384) {     // W1 [128][128] -> [128][128]^T
            int j = i - 262144;
            int k = j >> 7, n = j & 127;
            ws[OFF_SW1T + n * 128 + k] = f2bf(sW1[j]);
            ws[OFF_TW1T + n * 128 + k] = f2bf(tW1[j]);
        } else {                             // W2 [128][2048] -> [2048][128]
            int j = i - (262144 + 16384);
            int k = j >> 11, n = j & 2047;
            ws[OFF_SW2T + n * 128 + k] = f2bf(sW2[j]);
            ws[OFF_TW2T + n * 128 + k] = f2bf(tW2[j]);
        }
    }
}

__global__ __launch_bounds__(256, 2) void coupling_main(
    const float* __restrict__ z,
    const float* __restrict__ s_b2,
    const float* __restrict__ t_b2,
    const unsigned short* __restrict__ ws,
    float* __restrict__ f_out,
    float* __restrict__ d_vec) {

    __shared__ __align__(16) unsigned short Az[32 * 64];    // z_a chunk, XOR-swizzled
    __shared__ __align__(16) unsigned short Hs[32 * 128];   // h (s-net), swizzled
    __shared__ __align__(16) unsigned short Ht[32 * 128];   // h (t-net), swizzled
    __shared__ float Dred[128];

    const int tid  = threadIdx.x;
    const int wave = tid >> 6;
    const int lane = tid & 63;
    const int l15  = lane & 15;
    const int l4   = lane >> 4;
    const int brow = blockIdx.x * 32;

    const float2* __restrict__ zf2 = (const float2*)z;
    float2* __restrict__ ff2 = (float2*)f_out;

    const unsigned short* W0T[2] = { ws + OFF_SW0T, ws + OFF_TW0T };
    const unsigned short* W1T[2] = { ws + OFF_SW1T, ws + OFF_TW1T };
    const unsigned short* W2T[2] = { ws + OFF_SW2T, ws + OFF_TW2T };

    // ---------------- layer 0: h0 = leaky(z_a @ W0) for both nets ----------------
    f32x4 acc0[2][2][2] = {};   // [net][m2][n2]

    for (int kk = 0; kk < 2048; kk += 64) {
        __syncthreads();   // protect Az vs previous iteration's reads
        // stage z_a chunk: 8 rows per wave, 64 k-values per row (one wave-load)
        #pragma unroll
        for (int i = 0; i < 8; ++i) {
            const int row = wave * 8 + i;
            const float2 v = zf2[(size_t)(brow + row) * 2048 + kk + lane];
            const int rl = (kk + lane) >> 5;            // lattice row of this k
            const float a = (rl & 1) ? v.y : v.x;       // A-site: c == r (mod 2)
            Az[row * 64 + (lane ^ ((row & 7) << 3))] = f2bf(a);
        }
        __syncthreads();

        bf16x8 af[2][2];   // [m2][k2]
        #pragma unroll
        for (int m2 = 0; m2 < 2; ++m2)
            #pragma unroll
            for (int k2 = 0; k2 < 2; ++k2) {
                const int row = m2 * 16 + l15;
                af[m2][k2] = *(const bf16x8*)&Az[row * 64 +
                               ((k2 * 32 + l4 * 8) ^ ((row & 7) << 3))];
            }
        #pragma unroll
        for (int net = 0; net < 2; ++net)
            #pragma unroll
            for (int n2 = 0; n2 < 2; ++n2) {
                const int n = wave * 32 + n2 * 16 + l15;
                #pragma unroll
                for (int k2 = 0; k2 < 2; ++k2) {
                    const bf16x8 bfr = *(const bf16x8*)&W0T[net][n * 2048 + kk + k2 * 32 + l4 * 8];
                    #pragma unroll
                    for (int m2 = 0; m2 < 2; ++m2)
                        acc0[net][m2][n2] = __builtin_amdgcn_mfma_f32_16x16x32_bf16(
                            af[m2][k2], bfr, acc0[net][m2][n2], 0, 0, 0);
                }
            }
    }

    // leaky relu, h0 -> LDS (swizzled)
    #pragma unroll
    for (int net = 0; net < 2; ++net) {
        unsigned short* H = net ? Ht : Hs;
        #pragma unroll
        for (int m2 = 0; m2 < 2; ++m2)
            #pragma unroll
            for (int n2 = 0; n2 < 2; ++n2)
                #pragma unroll
                for (int r = 0; r < 4; ++r) {
                    float v = acc0[net][m2][n2][r];
                    v = v > 0.0f ? v : SLOPE * v;
                    const int row = m2 * 16 + l4 * 4 + r;
                    const int col = wave * 32 + n2 * 16 + l15;
                    H[row * 128 + (col ^ ((row & 7) << 3))] = f2bf(v);
                }
    }
    __syncthreads();

    // ---------------- layer 1: h1 = leaky(h0 @ W1) ----------------
    f32x4 acc1[2][2][2] = {};
    #pragma unroll
    for (int k4 = 0; k4 < 4; ++k4) {
        bf16x8 ah[2][2];   // [net][m2]
        #pragma unroll
        for (int m2 = 0; m2 < 2; ++m2) {
            const int row = m2 * 16 + l15;
            const int e = row * 128 + ((k4 * 32 + l4 * 8) ^ ((row & 7) << 3));
            ah[0][m2] = *(const bf16x8*)&Hs[e];
            ah[1][m2] = *(const bf16x8*)&Ht[e];
        }
        #pragma unroll
        for (int net = 0; net < 2; ++net)
            #pragma unroll
            for (int n2 = 0; n2 < 2; ++n2) {
                const int n = wave * 32 + n2 * 16 + l15;
                const bf16x8 bfr = *(const bf16x8*)&W1T[net][n * 128 + k4 * 32 + l4 * 8];
                #pragma unroll
                for (int m2 = 0; m2 < 2; ++m2)
                    acc1[net][m2][n2] = __builtin_amdgcn_mfma_f32_16x16x32_bf16(
                        ah[net][m2], bfr, acc1[net][m2][n2], 0, 0, 0);
            }
    }
    __syncthreads();   // all h0 reads done before overwrite
    #pragma unroll
    for (int net = 0; net < 2; ++net) {
        unsigned short* H = net ? Ht : Hs;
        #pragma unroll
        for (int m2 = 0; m2 < 2; ++m2)
            #pragma unroll
            for (int n2 = 0; n2 < 2; ++n2)
                #pragma unroll
                for (int r = 0; r < 4; ++r) {
                    float v = acc1[net][m2][n2][r];
                    v = v > 0.0f ? v : SLOPE * v;
                    const int row = m2 * 16 + l4 * 4 + r;
                    const int col = wave * 32 + n2 * 16 + l15;
                    H[row * 128 + (col ^ ((row & 7) << 3))] = f2bf(v);
                }
    }
    __syncthreads();

    // ---------------- layer 2 + epilogue, 16 N-chunks of 128 cols ----------------
    float dsum[2][4] = {};
    for (int c = 0; c < 16; ++c) {
        const int jw = c * 128 + wave * 32;   // this wave's 32 cols = lattice row jw>>5
        f32x4 acc2[2][2][2] = {};
        #pragma unroll
        for (int k4 = 0; k4 < 4; ++k4) {
            bf16x8 ah[2][2];
            #pragma unroll
            for (int m2 = 0; m2 < 2; ++m2) {
                const int row = m2 * 16 + l15;
                const int e = row * 128 + ((k4 * 32 + l4 * 8) ^ ((row & 7) << 3));
                ah[0][m2] = *(const bf16x8*)&Hs[e];
                ah[1][m2] = *(const bf16x8*)&Ht[e];
            }
            #pragma unroll
            for (int net = 0; net < 2; ++net)
                #pragma unroll
                for (int n2 = 0; n2 < 2; ++n2) {
                    const int n = jw + n2 * 16 + l15;
                    const bf16x8 bfr = *(const bf16x8*)&W2T[net][n * 128 + k4 * 32 + l4 * 8];
                    #pragma unroll
                    for (int m2 = 0; m2 < 2; ++m2)
                        acc2[net][m2][n2] = __builtin_amdgcn_mfma_f32_16x16x32_bf16(
                            ah[net][m2], bfr, acc2[net][m2][n2], 0, 0, 0);
                }
        }
        const int rl = jw >> 5;          // lattice row index
        const int evenA = 1 - (rl & 1);  // A-sites at even z-cols when lattice row even
        #pragma unroll
        for (int n2 = 0; n2 < 2; ++n2) {
            const int p = n2 * 16 + l15;         // site-pair index within lattice row
            const float sb = s_b2[jw + p];
            const float tb = t_b2[jw + p];
            #pragma unroll
            for (int m2 = 0; m2 < 2; ++m2)
                #pragma unroll
                for (int r = 0; r < 4; ++r) {
                    const float sv = acc2[0][m2][n2][r] + sb;
                    const float tv = acc2[1][m2][n2][r] + tb;
                    const size_t zi = (size_t)(brow + m2 * 16 + l4 * 4 + r) * 2048 + rl * 32 + p;
                    const float2 zv = zf2[zi];
                    const float za = evenA ? zv.x : zv.y;
                    const float zb = evenA ? zv.y : zv.x;
                    const float fb = (zb - tv) * __expf(-sv);
                    float2 fv;
                    if (evenA) { fv.x = za; fv.y = fb; }
                    else       { fv.x = fb; fv.y = za; }
                    ff2[zi] = fv;
                    dsum[m2][r] += sv;
                }
        }
    }

    // ---------------- d reduction ----------------
    #pragma unroll
    for (int m2 = 0; m2 < 2; ++m2)
        #pragma unroll
        for (int r = 0; r < 4; ++r) {
            float v = dsum[m2][r];
            v += __shfl_xor(v, 1);
            v += __shfl_xor(v, 2);
            v += __shfl_xor(v, 4);
            v += __shfl_xor(v, 8);
            if (l15 == 0) Dred[wave * 32 + m2 * 16 + l4 * 4 + r] = v;
        }
    __syncthreads();
    if (tid < 32)
        d_vec[brow + tid] = Dred[tid] + Dred[32 + tid] + Dred[64 + tid] + Dred[96 + tid];
}

extern "C" void kernel_launch(void* const* d_in, const int* in_sizes, int n_in,
                              void* d_out, int out_size, void* d_ws, size_t ws_size,
                              hipStream_t stream) {
    const float* z   = (const float*)d_in[0];
    const float* sW0 = (const float*)d_in[1];
    const float* sW1 = (const float*)d_in[2];
    const float* sW2 = (const float*)d_in[3];
    const float* sb2 = (const float*)d_in[4];
    const float* tW0 = (const float*)d_in[5];
    const float* tW1 = (const float*)d_in[6];
    const float* tW2 = (const float*)d_in[7];
    const float* tb2 = (const float*)d_in[8];

    float* fout = (float*)d_out;
    float* dvec = fout + (size_t)BATCH * NSITES;
    unsigned short* ws = (unsigned short*)d_ws;

    hipLaunchKernelGGL(conv_w, dim3(512), dim3(256), 0, stream,
                       sW0, sW1, sW2, tW0, tW1, tW2, ws);
    hipLaunchKernelGGL(coupling_main, dim3(BATCH / 32), dim3(256), 0, stream,
                       z, sb2, tb2, ws, fout, dvec);
}